// Round 17
// baseline (80.643 us; speedup 1.0000x reference)
//
#include <hip/hip_runtime.h>

namespace {

constexpr int Cn   = 256;
constexpr int Hh   = 128;
constexpr int Ww   = 128;
constexpr int HW   = Hh * Ww;
constexpr int TILE = 16;
constexpr int CCH  = 8;              // channels per LDS chunk
constexpr int NCH  = Cn / CCH;       // 32 chunks
constexpr int HALO = 4;
constexpr int X2T  = 24;             // staged rows/cols
constexpr int X2S  = 24;             // LINEAR stride (gload_lds needs linear dest);
                                     //  ~2-way read aliasing = ~free (m136)
constexpr int X2CH = X2T * X2S;      // 576 floats per channel
constexpr int X1CH = TILE * TILE;    // 256 floats per channel
constexpr int NOFF = 81;

// 576 threads = 9 waves; wave wv <-> window row di = wv (o = 9*wv + dj).
// Lane l: h = l>>2 (tile row), m = l&3 (cols 4m..4m+3).
// r17 = r16 + x1 ALSO via global_load_lds. Evidence: r12 (reg-staged) and
// r16 (gload_lds x2) are IDENTICAL at ~101us profiled -> staging was never
// the path; the per-phase x1 global loads inside compute (load-to-use = 0
// at VGPR 56) were. Now both inputs burst at phase top (~27KB in flight),
// compute is pure LDS+VALU. x1 LDS read: lane l -> granule l, conflict-free.

__device__ __forceinline__ void gl2lds16(const float* g, float* l) {
  __builtin_amdgcn_global_load_lds(
      (const __attribute__((address_space(1))) void*)g,
      (__attribute__((address_space(3))) void*)l, 16, 0, 0);
}

__global__ __launch_bounds__(576, 1)
void costvol_kernel(const float* __restrict__ x1,
                    const float* __restrict__ x2,
                    const float* __restrict__ zp,   // >=16B of zeros (d_ws)
                    float* __restrict__ out)
{
  __shared__ float sx2[2][CCH * X2CH];   // 2 x 18,432 B
  __shared__ float sx1[2][CCH * X1CH];   // 2 x  8,192 B   (53,248 B total)

  const int t    = threadIdx.x;
  const int wv   = t >> 6;             // di = 0..8
  const int lane = t & 63;
  const int h    = lane >> 2;          // tile row 0..15
  const int m    = lane & 3;           // pixel group: cols 4m..4m+3

  const int tx = blockIdx.x, ty = blockIdx.y, b = blockIdx.z;
  const int x0 = tx * TILE, y0 = ty * TILE;

  const float* g2 = x2 + (size_t)b * Cn * HW;

  // ---- x2 staging: slot s = t + 576*j -> ch=s/144, row=(s%144)/6, col4=s%6;
  //      dest float4 idx = s (linear). OOB halo granule -> zp, inc 0. ----
  const float* gp0;  size_t inc0;
  const float* gp1;  size_t inc1;
  {
    const int s = t, ch = s / 144, rem = s % 144, row = rem / 6, c4 = rem % 6;
    const int gy = y0 - HALO + row, gx = x0 - HALO + 4 * c4;
    const bool ok = ((unsigned)gy < (unsigned)Hh) && (gx >= 0) && (gx + 3 < Ww);
    gp0  = ok ? (g2 + (size_t)ch * HW + (size_t)gy * Ww + gx) : zp;
    inc0 = ok ? (size_t)(CCH * HW) : 0;
  }
  {
    const int s = t + 576, ch = s / 144, rem = s % 144, row = rem / 6, c4 = rem % 6;
    const int gy = y0 - HALO + row, gx = x0 - HALO + 4 * c4;
    const bool ok = ((unsigned)gy < (unsigned)Hh) && (gx >= 0) && (gx + 3 < Ww);
    gp1  = ok ? (g2 + (size_t)ch * HW + (size_t)gy * Ww + gx) : zp;
    inc1 = ok ? (size_t)(CCH * HW) : 0;
  }
  const int lds0 = (t >> 6) * 256;          // wave-uniform float offsets
  const int lds1 = lds0 + 9 * 256;

  // ---- x1 staging: wave w (w<8) stages channel (k*CCH+w)'s 16x16 tile;
  //      lane l -> float4 idx 64*w + l -> [ch=w][row=h][col=4m] (always in). --
  const float* gpx;  size_t incx;
  if (wv < 8) {
    gpx  = x1 + (size_t)b * Cn * HW + (size_t)wv * HW
             + (size_t)(y0 + h) * Ww + (x0 + 4 * m);
    incx = (size_t)(CCH * HW);
  } else {
    gpx  = zp;
    incx = 0;
  }
  const int ldsx = wv * X1CH;               // wave-uniform (wv<8 used)

  float acc[9][4];
#pragma unroll
  for (int d = 0; d < 9; ++d)
#pragma unroll
    for (int p = 0; p < 4; ++p) acc[d][p] = 0.0f;

  const int rbase = (h + wv) * X2S + 4 * m;
  const int abase = h * TILE + 4 * m;       // x1 LDS read: granule l exactly

  // ---- batched 4-channel group: pure-LDS operands, then 144 FMAs ----
  auto quad = [&](int hc, const float* sc, const float* s1c) {
    float4 a[4];
    float  w[4][12];
#pragma unroll
    for (int cc = 0; cc < 4; ++cc) {
      a[cc] = *reinterpret_cast<const float4*>(s1c + (4 * hc + cc) * X1CH + abase);
      const float* bp = sc + (4 * hc + cc) * X2CH + rbase;
      *reinterpret_cast<float4*>(w[cc])     = *reinterpret_cast<const float4*>(bp);
      *reinterpret_cast<float4*>(w[cc] + 4) = *reinterpret_cast<const float4*>(bp + 4);
      *reinterpret_cast<float4*>(w[cc] + 8) = *reinterpret_cast<const float4*>(bp + 8);
    }
#pragma unroll
    for (int cc = 0; cc < 4; ++cc)
#pragma unroll
      for (int dj = 0; dj < 9; ++dj) {
        acc[dj][0] = fmaf(a[cc].x, w[cc][dj + 0], acc[dj][0]);
        acc[dj][1] = fmaf(a[cc].y, w[cc][dj + 1], acc[dj][1]);
        acc[dj][2] = fmaf(a[cc].z, w[cc][dj + 2], acc[dj][2]);
        acc[dj][3] = fmaf(a[cc].w, w[cc][dj + 3], acc[dj][3]);
      }
  };

  auto stage = [&](int nb) {
    gl2lds16(gp0, &sx2[nb][lds0]);  gp0 += inc0;
    gl2lds16(gp1, &sx2[nb][lds1]);  gp1 += inc1;
    if (wv < 8) { gl2lds16(gpx, &sx1[nb][ldsx]);  gpx += incx; }
  };

  // ---- prologue: stage chunk 0 ----
  stage(0);
  asm volatile("s_waitcnt vmcnt(0)" ::: "memory");
  __syncthreads();

  for (int k = 0; k < NCH; ++k) {
    if (k + 1 < NCH) stage((k + 1) & 1);     // burst both inputs at phase top
    const float* sc  = sx2[k & 1];
    const float* s1c = sx1[k & 1];
    quad(0, sc, s1c);
    quad(1, sc, s1c);
    asm volatile("s_waitcnt vmcnt(0)" ::: "memory");  // next chunk landed
    __syncthreads();
  }

  // ---- epilogue: o = 9*di + dj; each (b,o,y,x) written exactly once ----
  const float invc = 1.0f / (float)Cn;
  const int y  = y0 + h;
  const int xb = x0 + 4 * m;
#pragma unroll
  for (int dj = 0; dj < 9; ++dj) {
    const int o = wv * 9 + dj;
    float4 v;
    v.x = acc[dj][0] * invc;
    v.y = acc[dj][1] * invc;
    v.z = acc[dj][2] * invc;
    v.w = acc[dj][3] * invc;
    *reinterpret_cast<float4*>(out + (((size_t)b * NOFF + o) * Hh + y) * Ww + xb) = v;
  }
}

} // namespace

extern "C" void kernel_launch(void* const* d_in, const int* in_sizes, int n_in,
                              void* d_out, int out_size, void* d_ws, size_t ws_size,
                              hipStream_t stream) {
  const float* x1 = (const float*)d_in[0];
  const float* x2 = (const float*)d_in[1];
  float* out = (float*)d_out;

  hipMemsetAsync(d_ws, 0, 256, stream);   // 16B zero block for OOB halo

  dim3 grid(Ww / TILE, Hh / TILE, 4);   // 8 x 8 x 4 = 256 blocks (1/CU)
  dim3 block(576);                      // 9 waves: wave wv <-> window row di
  costvol_kernel<<<grid, block, 0, stream>>>(x1, x2, (const float*)d_ws, out);
}